// Round 1
// baseline (94.419 us; speedup 1.0000x reference)
//
#include <hip/hip_runtime.h>

// Problem constants (B,N,D,E) = (8,1024,128,8)
constexpr int B_ = 8, N_ = 1024, D_ = 128, E_ = 8;
constexpr int ROWS = B_ * N_;   // 8192 flattened (b,s) rows

typedef __attribute__((ext_vector_type(8))) short bf16x8;  // 8 bf16 (4 VGPRs)
typedef __attribute__((ext_vector_type(4))) float f32x4;   // MFMA accumulator

__device__ __forceinline__ short f2bf(float f) {
    // round-to-nearest-even f32 -> bf16 bit pattern
    union { float f; unsigned u; } v; v.f = f;
    return (short)((v.u + 0x7FFFu + ((v.u >> 16) & 1u)) >> 16);
}

// ---------------------------------------------------------------------------
// Kernel 1: coef[bs][e] = sum_o adj[bs][o] * edge[bs][o][e]
// One block per (b,s) row. adj row (4 KB) staged in LDS; edge row (32 KB)
// streamed as float4 (each float4 = one o, e in {0..3} or {4..7}).
// HBM-bound: 288 MB total.
// ---------------------------------------------------------------------------
__global__ __launch_bounds__(256)
void coef_kernel(const float* __restrict__ edge,   // (ROWS, N, E)
                 const float* __restrict__ adj,    // (ROWS, N)
                 float* __restrict__ coef)         // (ROWS, E)
{
    __shared__ float s_adj[N_];
    __shared__ float s_red[4][2][4];
    const int bs  = blockIdx.x;
    const int tid = threadIdx.x;

    // stage adj row: 1024 floats = 256 float4, one per thread
    ((float4*)s_adj)[tid] = ((const float4*)(adj + (size_t)bs * N_))[tid];
    __syncthreads();

    const float4* e4 = (const float4*)(edge + (size_t)bs * N_ * E_);
    float acc[4] = {0.f, 0.f, 0.f, 0.f};
    #pragma unroll
    for (int it = 0; it < 8; ++it) {
        float4 ev = e4[it * 256 + tid];               // coalesced 4 KB/iter/block
        float a = s_adj[(it * 1024 + tid * 4) >> 3];  // o for this float4
        acc[0] += a * ev.x; acc[1] += a * ev.y;
        acc[2] += a * ev.z; acc[3] += a * ev.w;
    }
    // thread holds partials for e = 4*(tid&1) + c. Reduce over lanes keeping
    // parity bit 0 intact (xor masks 2..32).
    #pragma unroll
    for (int m = 2; m <= 32; m <<= 1) {
        acc[0] += __shfl_xor(acc[0], m, 64);
        acc[1] += __shfl_xor(acc[1], m, 64);
        acc[2] += __shfl_xor(acc[2], m, 64);
        acc[3] += __shfl_xor(acc[3], m, 64);
    }
    const int lane = tid & 63, wv = tid >> 6;
    if (lane < 2) {   // lane 0: e 0..3 sums, lane 1: e 4..7 sums (this wave)
        #pragma unroll
        for (int c = 0; c < 4; ++c) s_red[wv][lane][c] = acc[c];
    }
    __syncthreads();
    if (tid < 8) {
        const int h = tid >> 2, c = tid & 3;
        coef[(size_t)bs * E_ + tid] =
            s_red[0][h][c] + s_red[1][h][c] + s_red[2][h][c] + s_red[3][h][c];
    }
}

// ---------------------------------------------------------------------------
// Kernel 2: out = A @ Wf  (8192 x 128, K = 1024 = e*128 + j)
//   A[r, e*128+j] = coef[r,e] * node[r,j]   (built on the fly)
//   Wf[e*128+j, i] = W[e,i,j]               (8 contiguous j per lane — direct
//                                            global reads; W is L2-resident)
// Block = 32 rows x 128 cols, 4 waves; wave w: rows 16*(w&1), cols 64*(w>>1),
// 4 x mfma_f32_16x16x32_bf16 accumulators per wave.
// ---------------------------------------------------------------------------
__global__ __launch_bounds__(256)
void gemm_kernel(const float* __restrict__ node,  // (ROWS, D)
                 const float* __restrict__ coef,  // (ROWS, E)
                 const float* __restrict__ W,     // (E, D, D)
                 float* __restrict__ out)         // (ROWS, D)
{
    const int tid  = threadIdx.x;
    const int wv   = tid >> 6;
    const int lane = tid & 63;
    const int l16  = lane & 15;
    const int lk   = lane >> 4;          // k-group 0..3
    const int rbase = blockIdx.x * 32 + 16 * (wv & 1);
    const int cbase = 64 * (wv >> 1);
    const int r = rbase + l16;           // A-row this lane supplies

    f32x4 acc[4] = {};

    const float* xrow = node + (size_t)r * D_;
    #pragma unroll 1
    for (int e = 0; e < E_; ++e) {
        const float cf = coef[r * E_ + e];
        const float* We = W + e * D_ * D_;
        #pragma unroll
        for (int js = 0; js < D_; js += 32) {   // K-step of 32 within this e
            const int j0 = js + lk * 8;
            // A fragment: bf16(coef * x[j0..j0+7])
            bf16x8 afrag;
            const float* xp = xrow + j0;
            #pragma unroll
            for (int t = 0; t < 8; ++t) afrag[t] = f2bf(cf * xp[t]);
            #pragma unroll
            for (int c = 0; c < 4; ++c) {
                // B fragment: lane supplies Wf[j0..j0+7, i] = W[e, i, j0..j0+7]
                const float* wp = We + (size_t)(cbase + 16 * c + l16) * D_ + j0;
                bf16x8 bfrag;
                #pragma unroll
                for (int t = 0; t < 8; ++t) bfrag[t] = f2bf(wp[t]);
                acc[c] = __builtin_amdgcn_mfma_f32_16x16x32_bf16(afrag, bfrag, acc[c], 0, 0, 0);
            }
        }
    }
    // C/D layout (HW-verified): col = lane&15, row = (lane>>4)*4 + reg
    #pragma unroll
    for (int c = 0; c < 4; ++c) {
        const int col = cbase + 16 * c + l16;
        #pragma unroll
        for (int t = 0; t < 4; ++t) {
            out[(size_t)(rbase + lk * 4 + t) * D_ + col] = acc[c][t];
        }
    }
}

extern "C" void kernel_launch(void* const* d_in, const int* in_sizes, int n_in,
                              void* d_out, int out_size, void* d_ws, size_t ws_size,
                              hipStream_t stream) {
    (void)in_sizes; (void)n_in; (void)out_size; (void)ws_size;
    const float* node = (const float*)d_in[0];   // (8,1024,128)
    const float* edge = (const float*)d_in[1];   // (8,1024,1024,8)
    const float* adj  = (const float*)d_in[2];   // (8,1024,1024)
    const float* W    = (const float*)d_in[3];   // (8,128,128)
    float* coef = (float*)d_ws;                  // 8192*8 f32 = 256 KB scratch

    coef_kernel<<<ROWS, 256, 0, stream>>>(edge, adj, coef);
    gemm_kernel<<<ROWS / 32, 256, 0, stream>>>(node, coef, W, (float*)d_out);
}

// Round 2
// 74.047 us; speedup vs baseline: 1.2751x; 1.2751x over previous
//
#include <hip/hip_runtime.h>

// Problem constants (B,N,D,E) = (8,1024,128,8)
constexpr int B_ = 8, N_ = 1024, D_ = 128, E_ = 8;
constexpr int ROWS = B_ * N_;   // 8192 flattened (b,s) rows

typedef __attribute__((ext_vector_type(8))) _Float16 f16x8;  // 8 f16 (4 VGPRs)
typedef __attribute__((ext_vector_type(4))) _Float16 f16x4;
typedef __attribute__((ext_vector_type(4))) float f32x4;     // MFMA accumulator

// ---------------------------------------------------------------------------
// Kernel 1 (unchanged from R1): coef[bs][e] = sum_o adj[bs][o]*edge[bs][o][e]
// One block per (b,s) row; adj row in LDS; edge streamed as float4.
// ---------------------------------------------------------------------------
__global__ __launch_bounds__(256)
void coef_kernel(const float* __restrict__ edge,   // (ROWS, N, E)
                 const float* __restrict__ adj,    // (ROWS, N)
                 float* __restrict__ coef)         // (ROWS, E)
{
    __shared__ float s_adj[N_];
    __shared__ float s_red[4][2][4];
    const int bs  = blockIdx.x;
    const int tid = threadIdx.x;

    ((float4*)s_adj)[tid] = ((const float4*)(adj + (size_t)bs * N_))[tid];
    __syncthreads();

    const float4* e4 = (const float4*)(edge + (size_t)bs * N_ * E_);
    float acc[4] = {0.f, 0.f, 0.f, 0.f};
    #pragma unroll
    for (int it = 0; it < 8; ++it) {
        float4 ev = e4[it * 256 + tid];
        float a = s_adj[(it * 1024 + tid * 4) >> 3];
        acc[0] += a * ev.x; acc[1] += a * ev.y;
        acc[2] += a * ev.z; acc[3] += a * ev.w;
    }
    #pragma unroll
    for (int m = 2; m <= 32; m <<= 1) {
        acc[0] += __shfl_xor(acc[0], m, 64);
        acc[1] += __shfl_xor(acc[1], m, 64);
        acc[2] += __shfl_xor(acc[2], m, 64);
        acc[3] += __shfl_xor(acc[3], m, 64);
    }
    const int lane = tid & 63, wv = tid >> 6;
    if (lane < 2) {
        #pragma unroll
        for (int c = 0; c < 4; ++c) s_red[wv][lane][c] = acc[c];
    }
    __syncthreads();
    if (tid < 8) {
        const int h = tid >> 2, c = tid & 3;
        coef[(size_t)bs * E_ + tid] =
            s_red[0][h][c] + s_red[1][h][c] + s_red[2][h][c] + s_red[3][h][c];
    }
}

// ---------------------------------------------------------------------------
// Prep: Wh[e][i][j] = f16(W[e][i][j]).  131072 elems, 4/thread.
// ---------------------------------------------------------------------------
__global__ __launch_bounds__(256)
void wprep_kernel(const float* __restrict__ W, _Float16* __restrict__ Wh)
{
    const int i = blockIdx.x * 256 + threadIdx.x;     // 32768 threads
    float4 v = ((const float4*)W)[i];
    f16x4 h;
    h[0] = (_Float16)v.x; h[1] = (_Float16)v.y;
    h[2] = (_Float16)v.z; h[3] = (_Float16)v.w;
    ((f16x4*)Wh)[i] = h;
}

// ---------------------------------------------------------------------------
// Kernel 2 v2: out = A @ Wf  (8192 x 128, K = 1024 = e*128 + j), f16 MFMA.
//   A[r, e*128+j] = coef[r,e] * node[r,j]   (built in registers)
//   Wf[e*128+j, i] = Wh[e][i][j]            (direct f16x8 loads, L2-resident)
// Block = 16 rows x 128 cols, 4 waves; wave w owns cols [32w, 32w+32).
// Grid = 512 blocks -> 2 blocks/CU, 2 waves/SIMD.
// ---------------------------------------------------------------------------
__global__ __launch_bounds__(256)
void gemm_kernel(const float* __restrict__ node,   // (ROWS, D)
                 const float* __restrict__ coef,   // (ROWS, E)
                 const _Float16* __restrict__ Wh,  // (E, D, D)
                 float* __restrict__ out)          // (ROWS, D)
{
    const int tid  = threadIdx.x;
    const int wv   = tid >> 6;           // col group
    const int lane = tid & 63;
    const int l16  = lane & 15;
    const int lk   = lane >> 4;          // k-group 0..3
    const int rbase = blockIdx.x * 16;
    const int cbase = 32 * wv;
    const int r = rbase + l16;           // A-row this lane supplies

    // Preload this lane's x slices: xv[q][t] = x[q*32 + lk*8 + t], q=0..3
    const float* xrow = node + (size_t)r * D_;
    float xv[4][8];
    #pragma unroll
    for (int q = 0; q < 4; ++q) {
        const float4* p = (const float4*)(xrow + q * 32 + lk * 8);
        float4 a = p[0], b = p[1];
        xv[q][0] = a.x; xv[q][1] = a.y; xv[q][2] = a.z; xv[q][3] = a.w;
        xv[q][4] = b.x; xv[q][5] = b.y; xv[q][6] = b.z; xv[q][7] = b.w;
    }

    f32x4 acc[2] = {};

    #pragma unroll 1
    for (int e = 0; e < E_; ++e) {
        const float cfe = coef[r * E_ + e];          // per-lane scalar, L1/L2 hit
        const _Float16* We = Wh + e * D_ * D_;
        #pragma unroll
        for (int js = 0; js < 4; ++js) {             // K-step of 32 within e
            f16x8 af;
            #pragma unroll
            for (int t = 0; t < 8; ++t) af[t] = (_Float16)(cfe * xv[js][t]);
            #pragma unroll
            for (int c = 0; c < 2; ++c) {
                const _Float16* wp = We + (size_t)(cbase + 16 * c + l16) * D_ + js * 32 + lk * 8;
                f16x8 bf = *(const f16x8*)wp;
                acc[c] = __builtin_amdgcn_mfma_f32_16x16x32_f16(af, bf, acc[c], 0, 0, 0);
            }
        }
    }
    // C/D layout: col = lane&15, row = (lane>>4)*4 + reg
    #pragma unroll
    for (int c = 0; c < 2; ++c) {
        const int col = cbase + 16 * c + l16;
        #pragma unroll
        for (int t = 0; t < 4; ++t) {
            out[(size_t)(rbase + lk * 4 + t) * D_ + col] = acc[c][t];
        }
    }
}

extern "C" void kernel_launch(void* const* d_in, const int* in_sizes, int n_in,
                              void* d_out, int out_size, void* d_ws, size_t ws_size,
                              hipStream_t stream) {
    (void)in_sizes; (void)n_in; (void)out_size; (void)ws_size;
    const float* node = (const float*)d_in[0];   // (8,1024,128)
    const float* edge = (const float*)d_in[1];   // (8,1024,1024,8)
    const float* adj  = (const float*)d_in[2];   // (8,1024,1024)
    const float* W    = (const float*)d_in[3];   // (8,128,128)

    float*     coef = (float*)d_ws;                        // 256 KB
    _Float16*  Wh   = (_Float16*)((char*)d_ws + 256*1024); // 256 KB

    wprep_kernel<<<128, 256, 0, stream>>>(W, Wh);
    coef_kernel<<<ROWS, 256, 0, stream>>>(edge, adj, coef);
    gemm_kernel<<<ROWS / 16, 256, 0, stream>>>(node, coef, Wh, (float*)d_out);
}